// Round 1
// baseline (469.175 us; speedup 1.0000x reference)
//
#include <hip/hip_runtime.h>
#include <hip/hip_bf16.h>
#include <cstdint>
#include <cstddef>

#define HID 512
#define B_SZ 32
#define T_SZ 4096

typedef __bf16 bf16x8 __attribute__((ext_vector_type(8)));
typedef float f32x4 __attribute__((ext_vector_type(4)));

__device__ __forceinline__ unsigned short f2bf_rne(float f) {
    unsigned int u = __float_as_uint(f);
    unsigned int r = (u + 0x7FFFu + ((u >> 16) & 1u)) >> 16;
    return (unsigned short)r;
}

// ---------------- kernel 1: s[b][n] = dot(dec[b,:], Ws[n,:]) ----------------
__global__ void k_s(const float* __restrict__ dec, const float* __restrict__ Ws,
                    float* __restrict__ s) {
    int idx = blockIdx.x * 256 + threadIdx.x;   // 16384 = 32*512
    int b = idx >> 9, n = idx & 511;
    const float4* dp = reinterpret_cast<const float4*>(dec + (size_t)b * HID);
    const float4* wp = reinterpret_cast<const float4*>(Ws + (size_t)n * HID);
    float acc = 0.f;
#pragma unroll 8
    for (int i = 0; i < HID / 4; ++i) {
        float4 d = dp[i], w = wp[i];
        acc += d.x * w.x + d.y * w.y + d.z * w.z + d.w * w.w;
    }
    s[idx] = acc;
}

// ------------- kernel 2: pack W_h (fp32 [512][512]) -> bf16 MFMA-frag order --
// Fragment layout for mfma_f32_16x16x32_bf16 B-operand:
//   lane = g*16 + c holds W[n4*16 + c][kk*32 + g*8 + j], j=0..7
// Packed as uint4 (8 bf16) at index (n4*16 + kk)*64 + lane.
__global__ void k_pack(const float* __restrict__ Wh, uint4* __restrict__ Wb) {
    int idx = blockIdx.x * 256 + threadIdx.x;   // 32768, 8 elems each
    int n = idx >> 6;
    int k0 = (idx & 63) * 8;
    const float4* p = reinterpret_cast<const float4*>(Wh + (size_t)n * HID + k0);
    float4 x0 = p[0], x1 = p[1];
    uint4 w;
    w.x = f2bf_rne(x0.x) | ((unsigned)f2bf_rne(x0.y) << 16);
    w.y = f2bf_rne(x0.z) | ((unsigned)f2bf_rne(x0.w) << 16);
    w.z = f2bf_rne(x1.x) | ((unsigned)f2bf_rne(x1.y) << 16);
    w.w = f2bf_rne(x1.z) | ((unsigned)f2bf_rne(x1.w) << 16);
    int n4 = n >> 4, c = n & 15, kk = k0 >> 5, g = (k0 >> 3) & 3;
    Wb[(size_t)(n4 * 16 + kk) * 64 + g * 16 + c] = w;
}

// ------------- kernel 3: fused h = enc@Wh^T ; e = tanh(h+s).v ---------------
// Block: 64 rows of (b,t), 256 threads = 4 waves. Waves split N=512 (128 each).
// A staged in LDS bf16 with XOR swizzle; W read from packed L2-resident Wb.
__global__ void __launch_bounds__(256) k_gemm_e(
    const float* __restrict__ enc, const uint4* __restrict__ Wb,
    const float* __restrict__ s, const float* __restrict__ v,
    float* __restrict__ e_out) {
    __shared__ __align__(16) unsigned char As[64 * 1024];  // 64 rows x 512 bf16 (swizzled)
    const int tid = threadIdx.x;
    const size_t row0 = (size_t)blockIdx.x * 64;
    const int b = (int)(row0 >> 12);   // row0 / 4096 (T divides tile)

    // ---- stage A: fp32 -> bf16, swizzle byte ^= ((row&7)<<4) ----
    for (int g = tid; g < 64 * 64; g += 256) {
        int row = g >> 6;
        int k0 = (g & 63) * 8;
        const float4* p = reinterpret_cast<const float4*>(enc + (row0 + row) * HID + k0);
        float4 x0 = p[0], x1 = p[1];
        uint4 w;
        w.x = f2bf_rne(x0.x) | ((unsigned)f2bf_rne(x0.y) << 16);
        w.y = f2bf_rne(x0.z) | ((unsigned)f2bf_rne(x0.w) << 16);
        w.z = f2bf_rne(x1.x) | ((unsigned)f2bf_rne(x1.y) << 16);
        w.w = f2bf_rne(x1.z) | ((unsigned)f2bf_rne(x1.w) << 16);
        int byte = row * 1024 + ((k0 * 2) ^ ((row & 7) << 4));
        *reinterpret_cast<uint4*>(&As[byte]) = w;
    }
    __syncthreads();

    const int lane = tid & 63, wid = tid >> 6;
    const int c = lane & 15, g4 = lane >> 4;

    float e_part[4][4] = {};   // [mi][r] partial over this lane's n-residues

    for (int nc = 0; nc < 2; ++nc) {
        f32x4 acc[4][4] = {};  // [mi][ni]
        for (int kk = 0; kk < 16; ++kk) {
            bf16x8 af[4];
#pragma unroll
            for (int mi = 0; mi < 4; ++mi) {
                int row = mi * 16 + c;
                int byte = row * 1024 + (((kk * 32 + g4 * 8) * 2) ^ ((row & 7) << 4));
                af[mi] = *reinterpret_cast<const bf16x8*>(&As[byte]);
            }
            bf16x8 bfr[4];
#pragma unroll
            for (int ni = 0; ni < 4; ++ni) {
                int n4 = wid * 8 + nc * 4 + ni;
                uint4 t = Wb[(size_t)(n4 * 16 + kk) * 64 + lane];
                bfr[ni] = *reinterpret_cast<bf16x8*>(&t);
            }
#pragma unroll
            for (int mi = 0; mi < 4; ++mi)
#pragma unroll
                for (int ni = 0; ni < 4; ++ni)
                    acc[mi][ni] = __builtin_amdgcn_mfma_f32_16x16x32_bf16(
                        af[mi], bfr[ni], acc[mi][ni], 0, 0, 0);
        }
        // epilogue: e_part += tanh(h + s[n]) * v[n]
#pragma unroll
        for (int ni = 0; ni < 4; ++ni) {
            int n = wid * 128 + nc * 64 + ni * 16 + c;
            float sn = s[b * HID + n];
            float vn = v[n];
#pragma unroll
            for (int mi = 0; mi < 4; ++mi)
#pragma unroll
                for (int r = 0; r < 4; ++r)
                    e_part[mi][r] += tanhf(acc[mi][ni][r] + sn) * vn;
        }
    }

    // reduce across the 16 n-residue lanes (bits 0..3 of lane)
#pragma unroll
    for (int m = 1; m <= 8; m <<= 1)
#pragma unroll
        for (int mi = 0; mi < 4; ++mi)
#pragma unroll
            for (int r = 0; r < 4; ++r)
                e_part[mi][r] += __shfl_xor(e_part[mi][r], m);

    __syncthreads();   // all waves done reading As -> safe to reuse as e_red
    float* e_red = reinterpret_cast<float*>(As);   // [4][64]
    if (c == 0) {
#pragma unroll
        for (int mi = 0; mi < 4; ++mi)
#pragma unroll
            for (int r = 0; r < 4; ++r)
                e_red[wid * 64 + mi * 16 + g4 * 4 + r] = e_part[mi][r];
    }
    __syncthreads();
    if (tid < 64)
        e_out[row0 + tid] = e_red[tid] + e_red[64 + tid] + e_red[128 + tid] + e_red[192 + tid];
}

// ---------------- kernel 4: masked softmax over T, in-place e->a ------------
__global__ void k_softmax(float* __restrict__ ea, const int* __restrict__ mask) {
    int b = blockIdx.x, tid = threadIdx.x;     // 1024 threads
    int lane = tid & 63, wid = tid >> 6;       // 16 waves
    __shared__ float red[16];
    float vals[4]; int ms[4];
    float mx = -1e30f;
#pragma unroll
    for (int j = 0; j < 4; ++j) {
        int t = tid + j * 1024;
        vals[j] = ea[(size_t)b * T_SZ + t];
        ms[j] = mask[(size_t)b * T_SZ + t];
        if (ms[j]) mx = fmaxf(mx, vals[j]);
    }
#pragma unroll
    for (int m = 32; m >= 1; m >>= 1) mx = fmaxf(mx, __shfl_xor(mx, m));
    if (lane == 0) red[wid] = mx;
    __syncthreads();
    if (tid == 0) {
        float m2 = red[0];
        for (int i = 1; i < 16; ++i) m2 = fmaxf(m2, red[i]);
        red[0] = m2;
    }
    __syncthreads();
    mx = red[0];
    __syncthreads();
    float p[4]; float sum = 0.f;
#pragma unroll
    for (int j = 0; j < 4; ++j) { p[j] = ms[j] ? expf(vals[j] - mx) : 0.f; sum += p[j]; }
#pragma unroll
    for (int m = 32; m >= 1; m >>= 1) sum += __shfl_xor(sum, m);
    if (lane == 0) red[wid] = sum;
    __syncthreads();
    if (tid == 0) {
        float s2 = 0.f;
        for (int i = 0; i < 16; ++i) s2 += red[i];
        red[0] = s2;
    }
    __syncthreads();
    float inv = 1.f / red[0];
#pragma unroll
    for (int j = 0; j < 4; ++j) {
        int t = tid + j * 1024;
        ea[(size_t)b * T_SZ + t] = p[j] * inv;
    }
}

// ---------------- kernel 5: ctx partials over T-chunks ----------------------
__global__ void k_ctx(const float* __restrict__ enc, const float* __restrict__ a,
                      float2* __restrict__ part) {
    int ts = blockIdx.x, b = blockIdx.y, tid = threadIdx.x;   // 32 x 32, 256 thr
    size_t rbase = (size_t)b * T_SZ + (size_t)ts * 128;
    const float2* ep = reinterpret_cast<const float2*>(enc + rbase * HID) + tid;
    const float* ap = a + rbase;
    float ax = 0.f, ay = 0.f, bx = 0.f, by = 0.f;
#pragma unroll 2
    for (int t = 0; t < 128; t += 2) {
        float a0 = ap[t], a1 = ap[t + 1];
        float2 e0 = ep[(size_t)t * 256], e1 = ep[(size_t)(t + 1) * 256];
        ax += a0 * e0.x; ay += a0 * e0.y;
        bx += a1 * e1.x; by += a1 * e1.y;
    }
    float2 r; r.x = ax + bx; r.y = ay + by;
    part[(size_t)(b * 32 + ts) * 256 + tid] = r;
}

// ---------------- kernel 6: reduce partials -> ctx --------------------------
__global__ void k_ctxred(const float* __restrict__ part, float* __restrict__ ctx) {
    int idx = blockIdx.x * 256 + threadIdx.x;   // 16384
    int b = idx >> 9, h = idx & 511;
    float sum = 0.f;
#pragma unroll
    for (int ts = 0; ts < 32; ++ts) sum += part[(size_t)(b * 32 + ts) * 512 + h];
    ctx[idx] = sum;
}

extern "C" void kernel_launch(void* const* d_in, const int* in_sizes, int n_in,
                              void* d_out, int out_size, void* d_ws, size_t ws_size,
                              hipStream_t stream) {
    const float* enc  = (const float*)d_in[0];   // [32,4096,512]
    const int*   mask = (const int*)d_in[1];     // [32,4096]
    const float* dec  = (const float*)d_in[2];   // [32,512]
    const float* Wh   = (const float*)d_in[3];   // [512,512]
    const float* Ws   = (const float*)d_in[4];   // [512,512]
    const float* v    = (const float*)d_in[5];   // [512]

    float* out = (float*)d_out;
    float* ctx = out;                // 16384 floats
    float* a   = out + 16384;        // 131072 floats (also e scratch)

    // ws layout (floats): s[16384] | Wb bf16 packed (131072 float-slots) | part[524288]
    // total 2.56 MB — requires ws_size >= 2.7 MB
    float* ws   = (float*)d_ws;
    float* s    = ws;
    uint4* Wb   = (uint4*)(ws + 16384);
    float* part = ws + 16384 + 131072;

    hipLaunchKernelGGL(k_s,      dim3(64),      dim3(256),  0, stream, dec, Ws, s);
    hipLaunchKernelGGL(k_pack,   dim3(128),     dim3(256),  0, stream, Wh, Wb);
    hipLaunchKernelGGL(k_gemm_e, dim3(2048),    dim3(256),  0, stream, enc, Wb, s, v, a);
    hipLaunchKernelGGL(k_softmax,dim3(32),      dim3(1024), 0, stream, a, mask);
    hipLaunchKernelGGL(k_ctx,    dim3(32, 32),  dim3(256),  0, stream, enc, a, (float2*)part);
    hipLaunchKernelGGL(k_ctxred, dim3(64),      dim3(256),  0, stream, part, ctx);
}

// Round 2
// 191.984 us; speedup vs baseline: 2.4438x; 2.4438x over previous
//
#include <hip/hip_runtime.h>
#include <hip/hip_bf16.h>
#include <cstdint>
#include <cstddef>

#define HID 512
#define T_SZ 4096

typedef __bf16 bf16x8 __attribute__((ext_vector_type(8)));
typedef float f32x4 __attribute__((ext_vector_type(4)));

__device__ __forceinline__ unsigned short f2bf_rne(float f) {
    unsigned int u = __float_as_uint(f);
    unsigned int r = (u + 0x7FFFu + ((u >> 16) & 1u)) >> 16;
    return (unsigned short)r;
}

__device__ __forceinline__ bf16x8 pack8(float4 x0, float4 x1) {
    bf16x8 r;
    r[0] = (__bf16)x0.x; r[1] = (__bf16)x0.y; r[2] = (__bf16)x0.z; r[3] = (__bf16)x0.w;
    r[4] = (__bf16)x1.x; r[5] = (__bf16)x1.y; r[6] = (__bf16)x1.z; r[7] = (__bf16)x1.w;
    return r;
}

__device__ __forceinline__ float fast_tanh(float x) {
    float e = __expf(2.0f * x);
    return 1.0f - 2.0f / (e + 1.0f);
}

__device__ __forceinline__ void gload_lds16(const void* g, void* l) {
    __builtin_amdgcn_global_load_lds(
        (const __attribute__((address_space(1))) unsigned int*)g,
        (__attribute__((address_space(3))) unsigned int*)l, 16, 0, 0);
}

// ---------------- kernel 1: s[b][n] = dot(dec[b,:], Ws[n,:]) ----------------
__global__ void k_s(const float* __restrict__ dec, const float* __restrict__ Ws,
                    float* __restrict__ s) {
    int idx = blockIdx.x * 256 + threadIdx.x;   // 16384 = 32*512
    int b = idx >> 9, n = idx & 511;
    const float4* dp = reinterpret_cast<const float4*>(dec + (size_t)b * HID);
    const float4* wp = reinterpret_cast<const float4*>(Ws + (size_t)n * HID);
    float acc = 0.f;
#pragma unroll 8
    for (int i = 0; i < HID / 4; ++i) {
        float4 d = dp[i], w = wp[i];
        acc += d.x * w.x + d.y * w.y + d.z * w.z + d.w * w.w;
    }
    s[idx] = acc;
}

// ------------- kernel 2: pack W_h -> bf16 fragments, gload_lds-linear order -
// Wb layout: chunk index = kk*2048 + n4g*64 + (g*16 + c), each chunk = uint4
// holding W[n4g*16 + c][kk*32 + g*8 + j], j=0..7 as bf16.
__global__ void k_pack(const float* __restrict__ Wh, uint4* __restrict__ Wb) {
    int idx = blockIdx.x * 256 + threadIdx.x;   // 32768, 8 elems each
    int n = idx >> 6;
    int k0 = (idx & 63) * 8;
    const float4* p = reinterpret_cast<const float4*>(Wh + (size_t)n * HID + k0);
    float4 x0 = p[0], x1 = p[1];
    uint4 w;
    w.x = f2bf_rne(x0.x) | ((unsigned)f2bf_rne(x0.y) << 16);
    w.y = f2bf_rne(x0.z) | ((unsigned)f2bf_rne(x0.w) << 16);
    w.z = f2bf_rne(x1.x) | ((unsigned)f2bf_rne(x1.y) << 16);
    w.w = f2bf_rne(x1.z) | ((unsigned)f2bf_rne(x1.w) << 16);
    int n4g = n >> 4, c = n & 15, kk = k0 >> 5, g = (k0 >> 3) & 3;
    Wb[(size_t)kk * 2048 + n4g * 64 + g * 16 + c] = w;
}

// ------------- kernel 3: fused h = enc@Wh^T ; e_part = sum tanh(h+s).v ------
// BM=64 rows, BN=256 cols (half of N), BK=32. 4 waves, each 64x64 output.
// Double-buffered LDS, prefetch one K-step ahead. 3 blocks/CU.
__global__ void __launch_bounds__(256, 3) k_gemm_e(
    const float* __restrict__ enc, const uint4* __restrict__ Wb,
    const float* __restrict__ s, const float* __restrict__ v,
    float* __restrict__ part_e) {
    __shared__ __align__(16) unsigned char Abuf[2][4096];    // 64 rows x 32 bf16
    __shared__ __align__(16) unsigned char Bbuf[2][16384];   // 16 n4-tiles x 64 chunks x 16B
    __shared__ float red[4][64];

    const int tid = threadIdx.x;
    // bijective XCD swizzle (grid = 4096 = 8 * 512): pairs (m, h=0/1) share XCD
    const int p = blockIdx.x;
    const int logical = (p & 7) * 512 + (p >> 3);
    const int h = logical & 1;
    const size_t row0 = (size_t)(logical >> 1) * 64;
    const int b = (int)(row0 >> 12);

    const int lane = tid & 63, wid = tid >> 6;
    const int c = lane & 15, g4 = lane >> 4;

    // preload epilogue constants (L2-resident)
    float sv_s[4], sv_v[4];
#pragma unroll
    for (int ni = 0; ni < 4; ++ni) {
        int n = h * 256 + wid * 64 + ni * 16 + c;
        sv_s[ni] = s[b * HID + n];
        sv_v[ni] = v[n];
    }

    // staging geometry
    const int ar = tid >> 2;                         // row 0..63
    const int ak = (tid & 3) * 8;                    // k-offset 0..24
    const float* Ag = enc + (row0 + ar) * HID + ak;  // + kk*32 per step
    const int abyte = ar * 64 + (tid & 3) * 16;
    const uint4* Bg = Wb + h * 1024;                 // + kk*2048 + chunk
    const int wchunk = wid * 64;                     // wave-uniform

    // ---- prologue: stage step 0, preload A regs for step 1 ----
    float4 a0 = *reinterpret_cast<const float4*>(Ag);
    float4 a1 = *reinterpret_cast<const float4*>(Ag + 4);
#pragma unroll
    for (int i = 0; i < 4; ++i)
        gload_lds16(Bg + (wchunk + i * 256) + (lane), &Bbuf[0][(wchunk + i * 256) * 16]);
    *reinterpret_cast<bf16x8*>(&Abuf[0][abyte]) = pack8(a0, a1);
    a0 = *reinterpret_cast<const float4*>(Ag + 32);
    a1 = *reinterpret_cast<const float4*>(Ag + 36);
    __syncthreads();

    f32x4 acc[4][4] = {};   // [mi][ni]

    for (int kk = 0; kk < 16; ++kk) {
        const int cur = kk & 1, nxt = cur ^ 1;
        if (kk < 15) {
            // issue B prefetch for kk+1
#pragma unroll
            for (int i = 0; i < 4; ++i)
                gload_lds16(Bg + (size_t)(kk + 1) * 2048 + (wchunk + i * 256) + lane,
                            &Bbuf[nxt][(wchunk + i * 256) * 16]);
            // write A(kk+1) from regs loaded last iteration
            *reinterpret_cast<bf16x8*>(&Abuf[nxt][abyte]) = pack8(a0, a1);
        }
        if (kk < 14) {
            a0 = *reinterpret_cast<const float4*>(Ag + (kk + 2) * 32);
            a1 = *reinterpret_cast<const float4*>(Ag + (kk + 2) * 32 + 4);
        }
        // compute step kk
        bf16x8 af[4], bfr[4];
#pragma unroll
        for (int mi = 0; mi < 4; ++mi)
            af[mi] = *reinterpret_cast<const bf16x8*>(&Abuf[cur][(mi * 16 + c) * 64 + g4 * 16]);
#pragma unroll
        for (int ni = 0; ni < 4; ++ni)
            bfr[ni] = *reinterpret_cast<const bf16x8*>(&Bbuf[cur][((wid * 4 + ni) * 64 + lane) * 16]);
#pragma unroll
        for (int mi = 0; mi < 4; ++mi)
#pragma unroll
            for (int ni = 0; ni < 4; ++ni)
                acc[mi][ni] = __builtin_amdgcn_mfma_f32_16x16x32_bf16(
                    af[mi], bfr[ni], acc[mi][ni], 0, 0, 0);
        __syncthreads();
    }

    // ---- epilogue: e_part[row] = sum_n tanh(h + s[n]) * v[n] over 256 n's ---
    float e_part[4][4] = {};   // [mi][r]
#pragma unroll
    for (int ni = 0; ni < 4; ++ni)
#pragma unroll
        for (int mi = 0; mi < 4; ++mi)
#pragma unroll
            for (int r = 0; r < 4; ++r)
                e_part[mi][r] += fast_tanh(acc[mi][ni][r] + sv_s[ni]) * sv_v[ni];

    // reduce across the 16 n-residue lanes (bits 0..3)
#pragma unroll
    for (int m = 1; m <= 8; m <<= 1)
#pragma unroll
        for (int mi = 0; mi < 4; ++mi)
#pragma unroll
            for (int r = 0; r < 4; ++r)
                e_part[mi][r] += __shfl_xor(e_part[mi][r], m);

    if (c == 0) {
#pragma unroll
        for (int mi = 0; mi < 4; ++mi)
#pragma unroll
            for (int r = 0; r < 4; ++r)
                red[wid][mi * 16 + g4 * 4 + r] = e_part[mi][r];
    }
    __syncthreads();
    if (tid < 64)
        part_e[(size_t)h * 131072 + row0 + tid] =
            red[0][tid] + red[1][tid] + red[2][tid] + red[3][tid];
}

// ---------------- kernel 4: e = part0+part1; masked softmax -> a ------------
__global__ void k_softmax(const float* __restrict__ part_e, float* __restrict__ a,
                          const int* __restrict__ mask) {
    int b = blockIdx.x, tid = threadIdx.x;     // 1024 threads
    int lane = tid & 63, wid = tid >> 6;       // 16 waves
    __shared__ float red[16];
    float vals[4]; int ms[4];
    float mx = -1e30f;
#pragma unroll
    for (int j = 0; j < 4; ++j) {
        size_t t = (size_t)b * T_SZ + tid + j * 1024;
        vals[j] = part_e[t] + part_e[131072 + t];
        ms[j] = mask[t];
        if (ms[j]) mx = fmaxf(mx, vals[j]);
    }
#pragma unroll
    for (int m = 32; m >= 1; m >>= 1) mx = fmaxf(mx, __shfl_xor(mx, m));
    if (lane == 0) red[wid] = mx;
    __syncthreads();
    if (tid == 0) {
        float m2 = red[0];
        for (int i = 1; i < 16; ++i) m2 = fmaxf(m2, red[i]);
        red[0] = m2;
    }
    __syncthreads();
    mx = red[0];
    __syncthreads();
    float pv[4]; float sum = 0.f;
#pragma unroll
    for (int j = 0; j < 4; ++j) { pv[j] = ms[j] ? __expf(vals[j] - mx) : 0.f; sum += pv[j]; }
#pragma unroll
    for (int m = 32; m >= 1; m >>= 1) sum += __shfl_xor(sum, m);
    if (lane == 0) red[wid] = sum;
    __syncthreads();
    if (tid == 0) {
        float s2 = 0.f;
        for (int i = 0; i < 16; ++i) s2 += red[i];
        red[0] = s2;
    }
    __syncthreads();
    float inv = 1.f / red[0];
#pragma unroll
    for (int j = 0; j < 4; ++j)
        a[(size_t)b * T_SZ + tid + j * 1024] = pv[j] * inv;
}

// ---------------- kernel 5: ctx partials over T-chunks ----------------------
__global__ void k_ctx(const float* __restrict__ enc, const float* __restrict__ a,
                      float2* __restrict__ part) {
    int ts = blockIdx.x, b = blockIdx.y, tid = threadIdx.x;   // 32 x 32, 256 thr
    size_t rbase = (size_t)b * T_SZ + (size_t)ts * 128;
    const float2* ep = reinterpret_cast<const float2*>(enc + rbase * HID) + tid;
    const float* ap = a + rbase;
    float ax = 0.f, ay = 0.f, bx = 0.f, by = 0.f;
#pragma unroll 2
    for (int t = 0; t < 128; t += 2) {
        float a0 = ap[t], a1 = ap[t + 1];
        float2 e0 = ep[(size_t)t * 256], e1 = ep[(size_t)(t + 1) * 256];
        ax += a0 * e0.x; ay += a0 * e0.y;
        bx += a1 * e1.x; by += a1 * e1.y;
    }
    float2 r; r.x = ax + bx; r.y = ay + by;
    part[(size_t)(b * 32 + ts) * 256 + tid] = r;
}

// ---------------- kernel 6: reduce partials -> ctx --------------------------
__global__ void k_ctxred(const float* __restrict__ part, float* __restrict__ ctx) {
    int idx = blockIdx.x * 256 + threadIdx.x;   // 16384
    int b = idx >> 9, h = idx & 511;
    float sum = 0.f;
#pragma unroll
    for (int ts = 0; ts < 32; ++ts) sum += part[(size_t)(b * 32 + ts) * 512 + h];
    ctx[idx] = sum;
}

extern "C" void kernel_launch(void* const* d_in, const int* in_sizes, int n_in,
                              void* d_out, int out_size, void* d_ws, size_t ws_size,
                              hipStream_t stream) {
    const float* enc  = (const float*)d_in[0];   // [32,4096,512]
    const int*   mask = (const int*)d_in[1];     // [32,4096]
    const float* dec  = (const float*)d_in[2];   // [32,512]
    const float* Wh   = (const float*)d_in[3];   // [512,512]
    const float* Ws   = (const float*)d_in[4];   // [512,512]
    const float* v    = (const float*)d_in[5];   // [512]

    float* out = (float*)d_out;
    float* ctx = out;                // 16384 floats
    float* a   = out + 16384;        // 131072 floats

    // ws layout (floats): s[16384] | Wb (131072 f-slots) | part_e[262144] | part[524288]
    float* ws     = (float*)d_ws;
    float* s      = ws;
    uint4* Wb     = (uint4*)(ws + 16384);
    float* part_e = ws + 16384 + 131072;
    float* part   = part_e + 262144;

    hipLaunchKernelGGL(k_s,      dim3(64),      dim3(256),  0, stream, dec, Ws, s);
    hipLaunchKernelGGL(k_pack,   dim3(128),     dim3(256),  0, stream, Wh, Wb);
    hipLaunchKernelGGL(k_gemm_e, dim3(4096),    dim3(256),  0, stream, enc, Wb, s, v, part_e);
    hipLaunchKernelGGL(k_softmax,dim3(32),      dim3(1024), 0, stream, part_e, a, mask);
    hipLaunchKernelGGL(k_ctx,    dim3(32, 32),  dim3(256),  0, stream, enc, a, (float2*)part);
    hipLaunchKernelGGL(k_ctxred, dim3(64),      dim3(256),  0, stream, part, ctx);
}